// Round 1
// 584.936 us; speedup vs baseline: 1.2031x; 1.2031x over previous
//
#include <hip/hip_runtime.h>
#include <hip/hip_bf16.h>

// ---------------- constants ----------------
#define N_NODES   30000
#define F_IN      768
#define HID       128
#define NHEAD     8
#define C_OUT     4

typedef short short8_t __attribute__((ext_vector_type(8)));
typedef float float4_t __attribute__((ext_vector_type(4)));
typedef int   int4_t   __attribute__((ext_vector_type(4)));

__device__ __forceinline__ float b2f(short u) {
    union { unsigned int i; float f; } v;
    v.i = ((unsigned int)(unsigned short)u) << 16;
    return v.f;
}
__device__ __forceinline__ short f2s(float f) {
    __hip_bfloat16 h = __float2bfloat16(f);
    short s; __builtin_memcpy(&s, &h, 2); return s;
}

// ---------------- workspace layout (bytes) ----------------
#define OFF_H_NEWS      0UL
#define OFF_H_INTER     7680000UL
#define OFF_OUT_NN      15360000UL
#define OFF_OUT_IN      23040000UL
#define OFF_ASRC_NN     30720000UL
#define OFF_ADST_NN     31680000UL
#define OFF_ASRC_IN     32640000UL
#define OFF_ADST_IN     33600000UL
#define OFF_WT_NEWS     34560000UL
#define OFF_WT_INTER    34756608UL
#define OFF_RS_NN       34953216UL
#define OFF_RS_IN       35073280UL
#define OFF_SORT_NN     35193344UL
#define OFF_SORT_IN     37113344UL
#define OFF_ZERO        40953344UL
#define OFF_DEG_NN      40953344UL
#define OFF_FILL_NN     41073408UL
#define OFF_DEG_IN      41193472UL
#define OFF_FILL_IN     41313536UL
#define OFF_SSUM        41433600UL   // 2*128 f32
#define OFF_CNT         41434624UL   // completion counter (16 B)
#define ZERO_BYTES      481296UL     // OFF_CNT+16 - OFF_ZERO  (multiple of 16)
#define OFF_BETA        41434640UL
#define OFF_FLAG        41434648UL
#define OFF_CPAR        41434656UL
#define OFF_WKT         41470512UL   // 16-aligned

// canonical param block element offsets
#define CP_B_NEWS  0
#define CP_B_INTER 128
#define CP_ASRC_NN 256
#define CP_ADST_NN 384
#define CP_ASRC_IN 512
#define CP_ADST_IN 640
#define CP_WK      768      // unused (wkT built from raw input)
#define CP_BK      17152
#define CP_Q       17280
#define CP_WOUT    17408
#define CP_BOUT    17920
#define CP_TOTAL   17924

// prep kernel block ranges
#define PREP_CONV_BLOCKS 7
#define PREP_TW_BLOCKS   384   // per weight
#define PREP_WK_BLOCKS   64
#define PREP_ZERO_BLOCKS 118
#define PREP_B0 PREP_CONV_BLOCKS                       // 7
#define PREP_B1 (PREP_B0 + 2*PREP_TW_BLOCKS)           // 775
#define PREP_B2 (PREP_B1 + PREP_WK_BLOCKS)             // 839
#define PREP_TOTAL (PREP_B2 + PREP_ZERO_BLOCKS)        // 957

#define GEMM_BX 469            // ceil(30000/64)

// ---------------- dtype detector ----------------
__global__ void detect_dtype(const unsigned int* __restrict__ x, int* __restrict__ flag) {
    __shared__ int cnt_s;
    if (threadIdx.x == 0) cnt_s = 0;
    __syncthreads();
    int sane = 0;
    for (int i = threadIdx.x; i < 16384; i += 1024) {
        unsigned int lo = x[i] & 0xFFFFu;
        unsigned int ex = (lo >> 7) & 0xFFu;
        if ((ex >= 107u && ex <= 147u) || lo == 0u || lo == 0x8000u) sane++;
    }
    atomicAdd(&cnt_s, sane);
    __syncthreads();
    if (threadIdx.x == 0) *flag = (cnt_s > 8192) ? 1 : 0;
}

// ---------------- fused prep: small-param convert + W transposes + wkT + zeroing ----------------
struct SmallParams {
    const void* src[10];
    int n[10];
    int dstoff[10];
};

__global__ void prep(SmallParams sp, short* __restrict__ cp,
                     const void* __restrict__ Wn, const void* __restrict__ Wi,
                     const void* __restrict__ Wkraw,
                     short* __restrict__ WtN, short* __restrict__ WtI,
                     short* __restrict__ wkT,
                     char* __restrict__ zbase,
                     const int* __restrict__ flag) {
    const bool isbf = (*flag != 0);
    int b = blockIdx.x, tid = threadIdx.x;
    if (b < PREP_B0) {
        int idx = b * 256 + tid;
        for (int s = 0; s < 10; ++s) {
            if (idx < sp.n[s]) {
                short v = isbf ? ((const short*)sp.src[s])[idx]
                               : f2s(((const float*)sp.src[s])[idx]);
                cp[sp.dstoff[s] + idx] = v;
                return;
            }
            idx -= sp.n[s];
        }
    } else if (b < PREP_B1) {
        int bb = b - PREP_B0;
        int ty = bb >= PREP_TW_BLOCKS;
        const void* Wraw = ty ? Wi : Wn;
        short* Wt        = ty ? WtI : WtN;
        int idx = (bb - ty * PREP_TW_BLOCKS) * 256 + tid;
        if (idx < F_IN * HID) {
            int n = idx / F_IN;
            int k = idx - n * F_IN;
            Wt[idx] = isbf ? ((const short*)Wraw)[k * HID + n]
                           : f2s(((const float*)Wraw)[k * HID + n]);
        }
    } else if (b < PREP_B2) {
        int idx = (b - PREP_B1) * 256 + tid;
        if (idx < HID * HID) {
            int j = idx >> 7;
            int k = idx & 127;
            wkT[idx] = isbf ? ((const short*)Wkraw)[k * HID + j]
                            : f2s(((const float*)Wkraw)[k * HID + j]);
        }
    } else {
        size_t off = ((size_t)(b - PREP_B2) * 256 + tid) * 16;
        if (off < ZERO_BYTES) *(int4_t*)(zbase + off) = (int4_t){0, 0, 0, 0};
    }
}

// ---------------- projection GEMM (+fused head dots) + degree count, one launch ----------------
#define BK   32
#define LDK  40

__global__ __launch_bounds__(256) void proj_count(
    const void* __restrict__ Xn, const void* __restrict__ Xi,
    const short* __restrict__ WtN, const short* __restrict__ WtI,
    const short* __restrict__ cp,
    short* __restrict__ Hn, short* __restrict__ Hi,
    float* __restrict__ asrc_nn, float* __restrict__ adst_nn,
    float* __restrict__ asrc_in, float* __restrict__ adst_in,
    const int* __restrict__ dnn, int Enn,
    const int* __restrict__ din, int Ein,
    int* __restrict__ deg_nn, int* __restrict__ deg_in,
    int M, const int* __restrict__ flag)
{
    __shared__ __align__(16) short As[64 * LDK];
    __shared__ __align__(16) short Bs[128 * LDK];

    int b = blockIdx.x;
    if (b >= 2 * GEMM_BX) {
        // ---- degree counting part ----
        int i = (b - 2 * GEMM_BX) * 256 + threadIdx.x;
        if (i < Enn) {
            int d = dnn[i];
            if ((unsigned)d < (unsigned)N_NODES) atomicAdd(&deg_nn[d], 1);
        } else {
            int j = i - Enn;
            if (j < Ein) {
                int d = din[j];
                if ((unsigned)d < (unsigned)N_NODES) atomicAdd(&deg_in[d], 1);
            }
        }
        return;
    }

    // ---- GEMM part ----
    const bool isbf = (*flag != 0);
    int ty = b >= GEMM_BX;
    int bx = b - ty * GEMM_BX;
    const void* Xraw = ty ? Xi : Xn;
    const short* Wt  = ty ? WtI : WtN;
    const short* bias = cp + (ty ? CP_B_INTER : CP_B_NEWS);
    short* Hout      = ty ? Hi : Hn;

    int m0   = bx * 64;
    int tid  = threadIdx.x;
    int lane = tid & 63;
    int wid  = tid >> 6;
    int quad = lane >> 4;
    int lm   = lane & 15;

    float4_t acc[8];
    #pragma unroll
    for (int c = 0; c < 8; ++c) acc[c] = (float4_t){0.f, 0.f, 0.f, 0.f};

    int sr  = tid >> 2;
    int skp = (tid & 3) * 8;

    for (int k0 = 0; k0 < F_IN; k0 += BK) {
        __syncthreads();
        {   // A tile
            int gm = m0 + sr; if (gm >= M) gm = M - 1;
            short8_t av;
            if (isbf) {
                av = *(const short8_t*)((const short*)Xraw + (size_t)gm * F_IN + k0 + skp);
            } else {
                const float* xf = (const float*)Xraw + (size_t)gm * F_IN + k0 + skp;
                float4_t f0 = *(const float4_t*)xf;
                float4_t f1 = *(const float4_t*)(xf + 4);
                av[0] = f2s(f0[0]); av[1] = f2s(f0[1]); av[2] = f2s(f0[2]); av[3] = f2s(f0[3]);
                av[4] = f2s(f1[0]); av[5] = f2s(f1[1]); av[6] = f2s(f1[2]); av[7] = f2s(f1[3]);
            }
            *(short8_t*)(&As[sr * LDK + skp]) = av;
        }
        #pragma unroll
        for (int rep = 0; rep < 2; ++rep) {
            int r = sr + rep * 64;
            short8_t bv = *(const short8_t*)(Wt + (size_t)r * F_IN + k0 + skp);
            *(short8_t*)(&Bs[r * LDK + skp]) = bv;
        }
        __syncthreads();

        short8_t bfrag[8];
        #pragma unroll
        for (int c = 0; c < 8; ++c)
            bfrag[c] = *(const short8_t*)(&Bs[(c * 16 + lm) * LDK + quad * 8]);
        short8_t afrag = *(const short8_t*)(&As[(wid * 16 + lm) * LDK + quad * 8]);
        #pragma unroll
        for (int c = 0; c < 8; ++c)
            acc[c] = __builtin_amdgcn_mfma_f32_16x16x32_bf16(afrag, bfrag[c], acc[c], 0, 0, 0);
    }

    // epilogue: store H and fused per-head attention dots.
    // C/D layout: col = c*16+lm, row = wid*16+quad*4+r.  Head h == register block c
    // (cols 16h..16h+15), so a 16-lane xor-reduce over lm yields the head dot.
    const short* aw0 = cp + (ty ? CP_ASRC_IN : CP_ASRC_NN);
    const short* aw1 = cp + CP_ADST_NN;
    const short* aw2 = cp + CP_ADST_IN;

    #pragma unroll
    for (int c = 0; c < 8; ++c) {
        int col = c * 16 + lm;
        float bv = b2f(bias[col]);
        float w0 = b2f(aw0[col]);
        float w1 = b2f(aw1[col]);
        float w2 = b2f(aw2[col]);
        #pragma unroll
        for (int r = 0; r < 4; ++r) {
            int gm = m0 + wid * 16 + quad * 4 + r;
            bool ok = gm < M;
            float hval = acc[c][r] + bv;
            if (ok) Hout[(size_t)gm * HID + col] = f2s(hval);
            if (ty == 0) {
                float d0 = hval * w0, d1 = hval * w1, d2 = hval * w2;
                #pragma unroll
                for (int off = 1; off < 16; off <<= 1) {
                    d0 += __shfl_xor(d0, off, 16);
                    d1 += __shfl_xor(d1, off, 16);
                    d2 += __shfl_xor(d2, off, 16);
                }
                if (lm == 0 && ok) {
                    asrc_nn[gm * NHEAD + c] = d0;
                    adst_nn[gm * NHEAD + c] = d1;
                    adst_in[gm * NHEAD + c] = d2;
                }
            } else {
                float d0 = hval * w0;
                #pragma unroll
                for (int off = 1; off < 16; off <<= 1)
                    d0 += __shfl_xor(d0, off, 16);
                if (lm == 0 && ok) asrc_in[gm * NHEAD + c] = d0;
            }
        }
    }
}

// ---------------- CSR prefix scan ----------------
__global__ __launch_bounds__(256) void prefix_scan2(
    const int* __restrict__ deg_nn, int* __restrict__ rs_nn,
    const int* __restrict__ deg_in, int* __restrict__ rs_in, int n)
{
    const int* deg = blockIdx.x ? deg_in : deg_nn;
    int* row_start = blockIdx.x ? rs_in : rs_nn;
    __shared__ int psum[256];
    int tid = threadIdx.x;
    int chunk = (n + 255) / 256;
    int lo = tid * chunk;
    int hi = lo + chunk; if (hi > n) hi = n; if (lo > n) lo = n;
    int s = 0;
    for (int i = lo; i < hi; ++i) s += deg[i];
    psum[tid] = s;
    __syncthreads();
    for (int off = 1; off < 256; off <<= 1) {
        int v = (tid >= off) ? psum[tid - off] : 0;
        __syncthreads();
        psum[tid] += v;
        __syncthreads();
    }
    int base = tid ? psum[tid - 1] : 0;
    for (int i = lo; i < hi; ++i) { row_start[i] = base; base += deg[i]; }
    if (tid == 255) row_start[n] = psum[255];
}

// ---------------- edge scatter ----------------
__global__ void scatter_edges2(const int* __restrict__ enn, int Enn,
                               const int* __restrict__ ein, int Ein,
                               const int* __restrict__ rs_nn, int* __restrict__ fill_nn,
                               int* __restrict__ sort_nn,
                               const int* __restrict__ rs_in, int* __restrict__ fill_in,
                               int* __restrict__ sort_in) {
    int i = blockIdx.x * 256 + threadIdx.x;
    if (i < Enn) {
        int d = enn[Enn + i];
        if (d >= 0 && d < N_NODES) {
            int pos = rs_nn[d] + atomicAdd(&fill_nn[d], 1);
            if (pos >= 0 && pos < Enn) sort_nn[pos] = enn[i];
        }
    } else {
        int j = i - Enn;
        if (j < Ein) {
            int d = ein[Ein + j];
            if (d >= 0 && d < N_NODES) {
                int pos = rs_in[d] + atomicAdd(&fill_in[d], 1);
                if (pos >= 0 && pos < Ein) sort_in[pos] = ein[j];
            }
        }
    }
}

// ---------------- fused edge-softmax + aggregation, wave-per-node ----------------
__global__ __launch_bounds__(256) void aggregate2(
    const short* __restrict__ Hnn, const short* __restrict__ Hin,
    const float* __restrict__ asrc_nn, const float* __restrict__ adst_nn,
    const float* __restrict__ asrc_in, const float* __restrict__ adst_in,
    const int* __restrict__ rs_nn, const int* __restrict__ rs_in,
    const int* __restrict__ sort_nn, const int* __restrict__ sort_in,
    short* __restrict__ out_nn, short* __restrict__ out_in)
{
    int tid = threadIdx.x, w = tid >> 6, lane = tid & 63;
    int type = blockIdx.y;
    const short* H    = type ? Hin : Hnn;
    const float* asrc = type ? asrc_in : asrc_nn;
    const float* adst = type ? adst_in : adst_nn;
    const int*   rs   = type ? rs_in : rs_nn;
    const int*   ss   = type ? sort_in : sort_nn;
    short* outb       = type ? out_in : out_nn;

    int dn = blockIdx.x * 4 + w;
    int start = rs[dn], end = rs[dn + 1];
    int head = lane >> 3;
    float adv = adst[dn * NHEAD + head];
    const short* Hl = H + lane * 2;

    float den = 0.f, a0 = 0.f, a1 = 0.f;
    for (int base = start; base < end; base += 64) {
        int nb = end - base; if (nb > 64) nb = 64;
        int myidx = 0;
        if (base + lane < end) {
            int t = ss[base + lane];
            myidx = (t < 0) ? 0 : (t >= N_NODES ? N_NODES - 1 : t);   // containment
        }
        int j = 0;
        for (; j + 2 <= nb; j += 2) {
            int s0 = __shfl(myidx, j, 64);
            int s1 = __shfl(myidx, j + 1, 64);
            float v0 = asrc[s0 * NHEAD + head];
            float v1 = asrc[s1 * NHEAD + head];
            unsigned int q0 = *(const unsigned int*)(Hl + (size_t)s0 * HID);
            unsigned int q1 = *(const unsigned int*)(Hl + (size_t)s1 * HID);
            float e0 = v0 + adv, e1 = v1 + adv;
            e0 = fmaxf(e0, 0.2f * e0); e1 = fmaxf(e1, 0.2f * e1);
            e0 = fminf(e0, 80.f);      e1 = fminf(e1, 80.f);
            float x0 = __expf(e0), x1 = __expf(e1);
            union { unsigned int u; float f; } cl0, ch0, cl1, ch1;
            cl0.u = q0 << 16; ch0.u = q0 & 0xFFFF0000u;
            cl1.u = q1 << 16; ch1.u = q1 & 0xFFFF0000u;
            den += x0; den += x1;
            a0 = fmaf(x0, cl0.f, a0); a0 = fmaf(x1, cl1.f, a0);
            a1 = fmaf(x0, ch0.f, a1); a1 = fmaf(x1, ch1.f, a1);
        }
        if (j < nb) {
            int s0 = __shfl(myidx, j, 64);
            float v0 = asrc[s0 * NHEAD + head];
            unsigned int q0 = *(const unsigned int*)(Hl + (size_t)s0 * HID);
            float e0 = v0 + adv;
            e0 = fmaxf(e0, 0.2f * e0);
            e0 = fminf(e0, 80.f);
            float x0 = __expf(e0);
            union { unsigned int u; float f; } cl0, ch0;
            cl0.u = q0 << 16; ch0.u = q0 & 0xFFFF0000u;
            den += x0;
            a0 = fmaf(x0, cl0.f, a0);
            a1 = fmaf(x0, ch0.f, a1);
        }
    }
    float inv = 1.f / (den + 1e-16f);
    unsigned int lo16 = (unsigned short)f2s(fmaxf(a0 * inv, 0.f));
    unsigned int hi16 = (unsigned short)f2s(fmaxf(a1 * inv, 0.f));
    *(unsigned int*)(outb + (size_t)dn * HID + lane * 2) = lo16 | (hi16 << 16);
}

// ---------------- semantic score via MFMA (+fused beta in last block) ----------------
__global__ __launch_bounds__(256) void score_mfma(
    const short* __restrict__ out_nn, const short* __restrict__ out_in,
    const short* __restrict__ wkT, const short* __restrict__ cp,
    float* __restrict__ Ssum, int* __restrict__ done_cnt,
    float* __restrict__ beta, int total_blocks)
{
    __shared__ float col_s[HID];
    __shared__ int lastflag;
    int tid  = threadIdx.x;
    int lane = tid & 63;
    int wid  = tid >> 6;
    int quad = lane >> 4;
    int lm   = lane & 15;
    const short* src = blockIdx.y ? out_in : out_nn;
    int m0 = blockIdx.x * 128;

    if (tid < HID) col_s[tid] = 0.f;
    __syncthreads();

    float4_t acc[2][8];
    #pragma unroll
    for (int i = 0; i < 2; ++i)
        #pragma unroll
        for (int c = 0; c < 8; ++c)
            acc[i][c] = (float4_t){0.f, 0.f, 0.f, 0.f};

    #pragma unroll
    for (int kc = 0; kc < 4; ++kc) {
        short8_t bfrag[8];
        #pragma unroll
        for (int c = 0; c < 8; ++c)
            bfrag[c] = *(const short8_t*)(wkT + (c * 16 + lm) * HID + kc * 32 + quad * 8);
        #pragma unroll
        for (int i = 0; i < 2; ++i) {
            int gm = m0 + wid * 32 + i * 16 + lm;
            if (gm >= N_NODES) gm = N_NODES - 1;
            short8_t afrag = *(const short8_t*)(src + (size_t)gm * HID + kc * 32 + quad * 8);
            #pragma unroll
            for (int c = 0; c < 8; ++c)
                acc[i][c] = __builtin_amdgcn_mfma_f32_16x16x32_bf16(afrag, bfrag[c], acc[i][c], 0, 0, 0);
        }
    }

    #pragma unroll
    for (int c = 0; c < 8; ++c) {
        int col = c * 16 + lm;
        float bkc = b2f(cp[CP_BK + col]);
        float lsum = 0.f;
        #pragma unroll
        for (int i = 0; i < 2; ++i)
            #pragma unroll
            for (int r = 0; r < 4; ++r) {
                int node = m0 + wid * 32 + i * 16 + quad * 4 + r;
                if (node < N_NODES) {
                    float a = acc[i][c][r] + bkc;
                    a = fminf(fmaxf(a, -15.f), 15.f);
                    float t = __expf(2.f * a);
                    lsum += (t - 1.f) / (t + 1.f);
                }
            }
        float v = lsum;
        v += __shfl_down(v, 32, 64);
        v += __shfl_down(v, 16, 64);
        if (quad == 0) atomicAdd(&col_s[col], v);
    }
    __syncthreads();
    if (tid < HID) atomicAdd(&Ssum[blockIdx.y * HID + tid], col_s[tid]);
    __syncthreads();

    // last finishing block computes beta
    if (tid == 0) {
        __threadfence();
        int old = atomicAdd(done_cnt, 1);
        lastflag = (old == total_blocks - 1) ? 1 : 0;
    }
    __syncthreads();
    if (lastflag && tid < 64) {
        float s00 = atomicAdd(&Ssum[tid], 0.f);
        float s01 = atomicAdd(&Ssum[tid + 64], 0.f);
        float s10 = atomicAdd(&Ssum[128 + tid], 0.f);
        float s11 = atomicAdd(&Ssum[192 + tid], 0.f);
        float q0 = b2f(cp[CP_Q + tid]), q1 = b2f(cp[CP_Q + tid + 64]);
        float v0 = q0 * s00 + q1 * s01;
        float v1 = q0 * s10 + q1 * s11;
        #pragma unroll
        for (int off = 32; off; off >>= 1) {
            v0 += __shfl_down(v0, off, 64);
            v1 += __shfl_down(v1, off, 64);
        }
        if (tid == 0) {
            float sc0 = v0 / (float)N_NODES;
            float sc1 = v1 / (float)N_NODES;
            float mx = fmaxf(sc0, sc1);
            float e0 = __expf(sc0 - mx), e1 = __expf(sc1 - mx);
            float inv = 1.f / (e0 + e1);
            beta[0] = e0 * inv;
            beta[1] = e1 * inv;
        }
    }
}

// ---------------- final: elu(beta0*out_nn + beta1*out_in) @ W_out + b_out ----------------
__global__ __launch_bounds__(256) void final_out(
    const short* __restrict__ out_nn, const short* __restrict__ out_in,
    const float* __restrict__ beta, const short* __restrict__ cp,
    void* __restrict__ Yraw, const int* __restrict__ flag)
{
    bool isbf = (*flag != 0);
    int tid = threadIdx.x, lane = tid & 63, w = tid >> 6;
    int n = blockIdx.x * 4 + w;
    float b0 = beta[0], b1 = beta[1];
    unsigned int u0 = *(const unsigned int*)(out_nn + (size_t)n * HID + lane * 2);
    unsigned int u1 = *(const unsigned int*)(out_in + (size_t)n * HID + lane * 2);
    union { unsigned int u; float f; } t;
    t.u = u0 << 16;          float f0 = b0 * t.f;
    t.u = u0 & 0xFFFF0000u;  float f1 = b0 * t.f;
    t.u = u1 << 16;          f0 += b1 * t.f;
    t.u = u1 & 0xFFFF0000u;  f1 += b1 * t.f;
    float e0 = (f0 > 0.f) ? f0 : expm1f(f0);
    float e1 = (f1 > 0.f) ? f1 : expm1f(f1);
    int c0 = lane * 2, c1 = lane * 2 + 1;
    float p[C_OUT];
    #pragma unroll
    for (int c = 0; c < C_OUT; ++c)
        p[c] = e0 * b2f(cp[CP_WOUT + c0 * C_OUT + c]) + e1 * b2f(cp[CP_WOUT + c1 * C_OUT + c]);
    #pragma unroll
    for (int off = 32; off; off >>= 1)
        #pragma unroll
        for (int c = 0; c < C_OUT; ++c) p[c] += __shfl_down(p[c], off, 64);
    if (lane == 0) {
        #pragma unroll
        for (int c = 0; c < C_OUT; ++c) {
            float r = p[c] + b2f(cp[CP_BOUT + c]);
            if (isbf) ((__hip_bfloat16*)Yraw)[n * C_OUT + c] = __float2bfloat16(r);
            else      ((float*)Yraw)[n * C_OUT + c] = r;
        }
    }
}

// ---------------- launch ----------------
extern "C" void kernel_launch(void* const* d_in, const int* in_sizes, int n_in,
                              void* d_out, int out_size, void* d_ws, size_t ws_size,
                              hipStream_t stream) {
    const void* x_news  = d_in[0];
    const void* x_inter = d_in[1];
    const int*  edge_nn = (const int*)d_in[2];
    const int*  edge_in = (const int*)d_in[3];

    int E_nn = in_sizes[2] / 2;
    int E_in = in_sizes[3] / 2;

    char* ws = (char*)d_ws;
    short* h_news  = (short*)(ws + OFF_H_NEWS);
    short* h_inter = (short*)(ws + OFF_H_INTER);
    short* out_nn  = (short*)(ws + OFF_OUT_NN);
    short* out_in  = (short*)(ws + OFF_OUT_IN);
    float* asrc_nn = (float*)(ws + OFF_ASRC_NN);
    float* adst_nn = (float*)(ws + OFF_ADST_NN);
    float* asrc_in = (float*)(ws + OFF_ASRC_IN);
    float* adst_in = (float*)(ws + OFF_ADST_IN);
    short* wt_news  = (short*)(ws + OFF_WT_NEWS);
    short* wt_inter = (short*)(ws + OFF_WT_INTER);
    int* rs_nn   = (int*)(ws + OFF_RS_NN);
    int* rs_in   = (int*)(ws + OFF_RS_IN);
    int* sort_nn = (int*)(ws + OFF_SORT_NN);
    int* sort_in = (int*)(ws + OFF_SORT_IN);
    int* deg_nn  = (int*)(ws + OFF_DEG_NN);
    int* fill_nn = (int*)(ws + OFF_FILL_NN);
    int* deg_in  = (int*)(ws + OFF_DEG_IN);
    int* fill_in = (int*)(ws + OFF_FILL_IN);
    float* Ssum  = (float*)(ws + OFF_SSUM);
    int*   dcnt  = (int*)(ws + OFF_CNT);
    float* beta  = (float*)(ws + OFF_BETA);
    int*   flag  = (int*)(ws + OFF_FLAG);
    short* cp    = (short*)(ws + OFF_CPAR);
    short* wkT   = (short*)(ws + OFF_WKT);

    detect_dtype<<<1, 1024, 0, stream>>>((const unsigned int*)x_news, flag);

    SmallParams sp;
    const int srcidx[10] = {5, 7, 8, 9, 10, 11, 13, 14, 15, 16};
    const int ns[10]     = {128, 128, 128, 128, 128, 128, 128, 128, 512, 4};
    const int doff[10]   = {CP_B_NEWS, CP_B_INTER, CP_ASRC_NN, CP_ADST_NN, CP_ASRC_IN,
                            CP_ADST_IN, CP_BK, CP_Q, CP_WOUT, CP_BOUT};
    for (int i = 0; i < 10; ++i) { sp.src[i] = d_in[srcidx[i]]; sp.n[i] = ns[i]; sp.dstoff[i] = doff[i]; }

    prep<<<PREP_TOTAL, 256, 0, stream>>>(sp, cp, d_in[4], d_in[6], d_in[12],
                                         wt_news, wt_inter, wkT, ws + OFF_ZERO, flag);

    int cnt_blocks = (E_nn + E_in + 255) / 256;
    proj_count<<<2 * GEMM_BX + cnt_blocks, 256, 0, stream>>>(
        x_news, x_inter, wt_news, wt_inter, cp, h_news, h_inter,
        asrc_nn, adst_nn, asrc_in, adst_in,
        edge_nn + E_nn, E_nn, edge_in + E_in, E_in, deg_nn, deg_in,
        N_NODES, flag);

    prefix_scan2<<<2, 256, 0, stream>>>(deg_nn, rs_nn, deg_in, rs_in, N_NODES);

    scatter_edges2<<<cnt_blocks, 256, 0, stream>>>(
        edge_nn, E_nn, edge_in, E_in, rs_nn, fill_nn, sort_nn, rs_in, fill_in, sort_in);

    aggregate2<<<dim3(N_NODES / 4, 2), 256, 0, stream>>>(
        h_news, h_inter, asrc_nn, adst_nn, asrc_in, adst_in,
        rs_nn, rs_in, sort_nn, sort_in, out_nn, out_in);

    int score_bx = (N_NODES + 127) / 128;
    score_mfma<<<dim3(score_bx, 2), 256, 0, stream>>>(
        out_nn, out_in, wkT, cp, Ssum, dcnt, beta, 2 * score_bx);

    final_out<<<N_NODES / 4, 256, 0, stream>>>(out_nn, out_in, beta, cp, d_out, flag);
}